// Round 1
// baseline (443.181 us; speedup 1.0000x reference)
//
#include <hip/hip_runtime.h>
#include <hip/hip_bf16.h>

typedef unsigned long long u64;
typedef unsigned int u32;

#define NTOT   54560   // anchors per batch (r + i)
#define NMOD   27280   // anchors per modality
#define BATCH  16
#define KPAD   1024
#define MAXD   1000

struct Ptrs { const float* p[30]; };

// ---------------- workspace layout (all 16B aligned) ----------------
constexpr size_t SZ_KEY   = (size_t)BATCH * NTOT * 8;       // u64 keys
constexpr size_t SZ_CLS   = (size_t)BATCH * NTOT * 4;       // int class
constexpr size_t SZ_BOX   = (size_t)BATCH * NTOT * 16;      // float4 boxes
constexpr size_t SZ_TOPK  = (size_t)BATCH * KPAD * 8;       // sorted keys
constexpr size_t SZ_T4    = (size_t)BATCH * KPAD * 16;      // float4 per-topk
constexpr size_t SZ_T1    = (size_t)BATCH * KPAD * 4;       // float per-topk
constexpr size_t SZ_VAL   = (size_t)BATCH * 32 * 4;         // valid bitset
constexpr size_t SZ_MASK  = (size_t)BATCH * KPAD * 32 * 4;  // iou mask bits

constexpr size_t OFF_KEY    = 0;
constexpr size_t OFF_CLS    = OFF_KEY   + SZ_KEY;
constexpr size_t OFF_BOX    = OFF_CLS   + SZ_CLS;
constexpr size_t OFF_TOPK   = OFF_BOX   + SZ_BOX;
constexpr size_t OFF_TRAW   = OFF_TOPK  + SZ_TOPK;
constexpr size_t OFF_TOFF   = OFF_TRAW  + SZ_T4;
constexpr size_t OFF_TAREA  = OFF_TOFF  + SZ_T4;
constexpr size_t OFF_TSCORE = OFF_TAREA + SZ_T1;
constexpr size_t OFF_TCLSF  = OFF_TSCORE+ SZ_T1;
constexpr size_t OFF_VALID  = OFF_TCLSF + SZ_T1;
constexpr size_t OFF_MASK   = OFF_VALID + SZ_VAL;

// ---------------- kernel A: decode all anchors ----------------
__global__ __launch_bounds__(256)
void decode_kernel(Ptrs ptrs, u64* __restrict__ keyAll, int* __restrict__ clsAll,
                   float4* __restrict__ boxAll) {
    int n = blockIdx.x * blockDim.x + threadIdx.x;
    int b = blockIdx.y;
    if (n >= NTOT) return;
    int mod = (n >= NMOD) ? 1 : 0;
    int nm = n - mod * NMOD;
    int l, pos, w, s;
    if (nm < 20480)      { l = 0; pos = nm;         w = 160; s = 8; }
    else if (nm < 25600) { l = 1; pos = nm - 20480; w = 80;  s = 16; }
    else if (nm < 26880) { l = 2; pos = nm - 25600; w = 40;  s = 32; }
    else if (nm < 27200) { l = 3; pos = nm - 26880; w = 20;  s = 64; }
    else                 { l = 4; pos = nm - 27200; w = 10;  s = 128; }
    int h = (w * 4) / 5;           // 128,64,32,16,8
    int hw = h * w;
    const float* clsP = ptrs.p[mod * 15 + l];
    const float* cntP = ptrs.p[mod * 15 + 5 + l];
    const float* regP = ptrs.p[mod * 15 + 10 + l];

    // class scores: sigmoid then max/argmax (first-index tie-break, matches jnp.argmax)
    const float* cb = clsP + (size_t)b * 20 * hw + pos;
    float best = -1.0f; int bi = 0;
    #pragma unroll
    for (int c = 0; c < 20; ++c) {
        float x = cb[(size_t)c * hw];
        float p = 1.0f / (1.0f + expf(-x));
        if (p > best) { best = p; bi = c; }
    }
    float cn = cntP[(size_t)b * hw + pos];
    float pc = 1.0f / (1.0f + expf(-cn));
    float score = sqrtf(__fmul_rn(best, pc));

    int xi = pos % w;
    int yi = pos / w;
    float cx = (float)(xi * s + (s >> 1));
    float cy = (float)(yi * s + (s >> 1));
    const float* rb = regP + (size_t)b * 4 * hw + pos;
    float r0 = rb[0], r1 = rb[(size_t)hw], r2 = rb[(size_t)2 * hw], r3 = rb[(size_t)3 * hw];
    float4 box;
    box.x = cx - r0; box.y = cy - r1; box.z = cx + r2; box.w = cy + r3;

    size_t o = (size_t)b * NTOT + n;
    // distinct 48-bit composite key: descending key order == (score desc, index asc)
    keyAll[o] = ((u64)__float_as_uint(score) << 16) | (u64)(65535 - n);
    clsAll[o] = bi + 1;
    boxAll[o] = box;
}

// ---------------- kernel B: exact top-1000 per batch (radix select + bitonic sort) ----------------
__global__ __launch_bounds__(1024)
void topk_kernel(const u64* __restrict__ keyAll, u64* __restrict__ topkey) {
    int b = blockIdx.x, tid = threadIdx.x;
    __shared__ u32 hist[256];
    __shared__ u64 s_prefix;
    __shared__ int s_remk;
    __shared__ u32 s_cnt;
    __shared__ u64 skey[KPAD];
    const u64* keys = keyAll + (size_t)b * NTOT;
    if (tid == 0) { s_prefix = 0ull; s_remk = MAXD; s_cnt = 0; }
    __syncthreads();
    for (int shift = 40; shift >= 0; shift -= 8) {
        if (tid < 256) hist[tid] = 0;
        __syncthreads();
        u64 pfx = s_prefix;
        int hi = shift + 8;
        for (int n = tid; n < NTOT; n += 1024) {
            u64 k = keys[n];
            if ((k >> hi) == (pfx >> hi))
                atomicAdd(&hist[(u32)(k >> shift) & 255u], 1u);
        }
        __syncthreads();
        if (tid == 0) {
            u32 cum = 0; int bin = 255; int rk = s_remk;
            for (; bin > 0; --bin) {
                u32 c = hist[bin];
                if (cum + c >= (u32)rk) break;
                cum += c;
            }
            s_prefix = pfx | ((u64)bin << shift);
            s_remk = rk - (int)cum;
        }
        __syncthreads();
    }
    u64 T = s_prefix;   // exactly the 1000th-largest key (all keys distinct)
    for (int n = tid; n < NTOT; n += 1024) {
        u64 k = keys[n];
        if (k >= T) {
            u32 p = atomicAdd(&s_cnt, 1u);
            if (p < KPAD) skey[p] = k;
        }
    }
    __syncthreads();
    if (tid >= (int)s_cnt) skey[tid] = 0ull;   // pad (real keys are all > 0)
    __syncthreads();
    // bitonic sort, descending
    for (int k2 = 2; k2 <= KPAD; k2 <<= 1) {
        for (int j = k2 >> 1; j > 0; j >>= 1) {
            int ixj = tid ^ j;
            if (ixj > tid) {
                u64 a = skey[tid], c = skey[ixj];
                bool seg = (tid & k2) == 0;
                bool sw = seg ? (a < c) : (a > c);
                if (sw) { skey[tid] = c; skey[ixj] = a; }
            }
            __syncthreads();
        }
    }
    topkey[(size_t)b * KPAD + tid] = skey[tid];
}

// ---------------- kernel C1: gather top-k, maxc, class-offset boxes, areas ----------------
__global__ __launch_bounds__(256)
void gather_kernel(const u64* __restrict__ topkey, const int* __restrict__ clsAll,
                   const float4* __restrict__ boxAll,
                   float4* __restrict__ traw, float4* __restrict__ toff,
                   float* __restrict__ tarea, float* __restrict__ tscore,
                   float* __restrict__ tclsf, u32* __restrict__ validbits) {
    #pragma clang fp contract(off)
    int b = blockIdx.x, tid = threadIdx.x;
    __shared__ float red[256];
    __shared__ u32 vb[32];
    __shared__ float s_maxc;
    if (tid < 32) vb[tid] = 0;
    __syncthreads();
    float lmax = -INFINITY;
    float4 raw[4]; float sc[4]; float cf[4];
    #pragma unroll
    for (int it = 0; it < 4; ++it) {
        int s2 = tid + it * 256;
        float4 bx = make_float4(0.f, 0.f, 0.f, 0.f);
        float score = 0.f, clsf = 0.f;
        if (s2 < MAXD) {
            u64 key = topkey[(size_t)b * KPAD + s2];
            int n = 65535 - (int)(key & 0xFFFFull);
            score = __uint_as_float((u32)(key >> 16));
            bx = boxAll[(size_t)b * NTOT + n];
            clsf = (float)clsAll[(size_t)b * NTOT + n];
            int valid = (score >= 0.05f) ? 1 : 0;
            // ref: maxc = max over (M,4) of where(valid, boxes, 0)
            float contrib = valid ? fmaxf(fmaxf(bx.x, bx.y), fmaxf(bx.z, bx.w)) : 0.0f;
            lmax = fmaxf(lmax, contrib);
            if (valid) atomicOr(&vb[s2 >> 5], 1u << (s2 & 31));
        }
        raw[it] = bx; sc[it] = score; cf[it] = clsf;
    }
    red[tid] = lmax;
    __syncthreads();
    for (int st = 128; st > 0; st >>= 1) {
        if (tid < st) red[tid] = fmaxf(red[tid], red[tid + st]);
        __syncthreads();
    }
    if (tid == 0) s_maxc = red[0];
    __syncthreads();
    float m1 = s_maxc + 1.0f;
    #pragma unroll
    for (int it = 0; it < 4; ++it) {
        int s2 = tid + it * 256;
        float4 bx = raw[it];
        float o = __fmul_rn(cf[it], m1);
        float4 ob;
        ob.x = __fadd_rn(bx.x, o); ob.y = __fadd_rn(bx.y, o);
        ob.z = __fadd_rn(bx.z, o); ob.w = __fadd_rn(bx.w, o);
        float dw = ob.z - ob.x + 1.0f;
        float dh = ob.w - ob.y + 1.0f;
        float area = __fmul_rn(dw, dh);
        size_t oo = (size_t)b * KPAD + s2;
        traw[oo] = bx; toff[oo] = ob; tarea[oo] = area;
        tscore[oo] = sc[it]; tclsf[oo] = cf[it];
    }
    if (tid < 32) validbits[b * 32 + tid] = vb[tid];
}

// ---------------- kernel C2: IoU > 0.6 suppression bitmask ----------------
__global__ __launch_bounds__(256)
void mask_kernel(const float4* __restrict__ toff, const float* __restrict__ tarea,
                 u32* __restrict__ maskG) {
    #pragma clang fp contract(off)
    int b = blockIdx.y;
    int i0 = blockIdx.x * 8;
    int tid = threadIdx.x;
    __shared__ float sx1[KPAD], sy1[KPAD], sx2[KPAD], sy2[KPAD], sa[KPAD];
    for (int t = tid; t < KPAD; t += 256) {
        float4 f = toff[(size_t)b * KPAD + t];
        sx1[t] = f.x; sy1[t] = f.y; sx2[t] = f.z; sy2[t] = f.w;
        sa[t] = tarea[(size_t)b * KPAD + t];
    }
    __syncthreads();
    int i = i0 + (tid >> 5);
    int w = tid & 31;
    float x1i = sx1[i], y1i = sy1[i], x2i = sx2[i], y2i = sy2[i], ai = sa[i];
    u32 bits = 0;
    for (int jj = 0; jj < 32; ++jj) {
        int j = w * 32 + jj;
        float iw = fminf(x2i, sx2[j]) - fmaxf(x1i, sx1[j]) + 1.0f;
        iw = fmaxf(iw, 0.0f);
        float ih = fminf(y2i, sy2[j]) - fmaxf(y1i, sy1[j]) + 1.0f;
        ih = fmaxf(ih, 0.0f);
        float inter = iw * ih;
        float denom = (ai + sa[j]) - inter;
        float iou = inter / denom;
        bits |= (iou > 0.6f) ? (1u << jj) : 0u;
    }
    maskG[((size_t)b * KPAD + i) * 32 + w] = bits;
}

// ---------------- kernel C3: sequential greedy scan (1 wave / batch) + outputs ----------------
__global__ __launch_bounds__(64)
void scan_out_kernel(const u32* __restrict__ maskG, const u32* __restrict__ validbits,
                     const float4* __restrict__ traw, const float* __restrict__ tscore,
                     const float* __restrict__ tclsf, float* __restrict__ out) {
    int b = blockIdx.x;
    int lane = threadIdx.x;
    int lw = lane & 31;
    const u32* mrow = maskG + (size_t)b * KPAD * 32;
    u32 vreg = (lane < 32) ? validbits[b * 32 + lane] : 0u;
    u32 removed = 0u, keepw = 0u;
    u32 m[8];
    #pragma unroll
    for (int d = 0; d < 8; ++d) m[d] = mrow[d * 32 + lw];
    for (int t = 0; t < 125; ++t) {
        #pragma unroll
        for (int d = 0; d < 8; ++d) {
            int i = t * 8 + d;
            int wi = i >> 5, bi2 = i & 31;
            u32 rw = (u32)__builtin_amdgcn_readlane((int)removed, wi);
            u32 vw = (u32)__builtin_amdgcn_readlane((int)vreg, wi);
            u32 k = ((vw >> bi2) & 1u) & (~(rw >> bi2) & 1u);
            if (k) removed |= m[d];
            if (lane == wi) keepw |= (k << bi2);
            m[d] = mrow[(size_t)(i + 8) * 32 + lw];   // prefetch (rows up to 1007 exist)
        }
    }
    __shared__ u32 keeps[32];
    if (lane < 32) keeps[lane] = keepw;
    __syncthreads();
    const int BQ = BATCH * MAXD;
    for (int s2 = lane; s2 < MAXD; s2 += 64) {
        u32 kf = (keeps[s2 >> 5] >> (s2 & 31)) & 1u;
        size_t oo = (size_t)b * KPAD + s2;
        float score = tscore[oo];
        float clsf = tclsf[oo];
        float4 bx = traw[oo];
        float x1 = fminf(fmaxf(bx.x, 0.f), 1279.f);
        float y1 = fminf(fmaxf(bx.y, 0.f), 1023.f);
        float x2 = fminf(fmaxf(bx.z, 0.f), 1279.f);
        float y2 = fminf(fmaxf(bx.w, 0.f), 1023.f);
        int base = b * MAXD + s2;
        out[base] = kf ? score : 0.0f;
        out[BQ + base] = kf ? clsf : 0.0f;
        float* ob = out + 2 * BQ + (size_t)base * 4;
        ob[0] = kf ? x1 : 0.f; ob[1] = kf ? y1 : 0.f;
        ob[2] = kf ? x2 : 0.f; ob[3] = kf ? y2 : 0.f;
        out[6 * BQ + base] = kf ? 1.0f : 0.0f;
    }
}

// ---------------- launch ----------------
extern "C" void kernel_launch(void* const* d_in, const int* in_sizes, int n_in,
                              void* d_out, int out_size, void* d_ws, size_t ws_size,
                              hipStream_t stream) {
    Ptrs ptrs;
    for (int i = 0; i < 30; ++i) ptrs.p[i] = (const float*)d_in[i];

    char* ws = (char*)d_ws;
    u64*    keyAll    = (u64*)   (ws + OFF_KEY);
    int*    clsAll    = (int*)   (ws + OFF_CLS);
    float4* boxAll    = (float4*)(ws + OFF_BOX);
    u64*    topkey    = (u64*)   (ws + OFF_TOPK);
    float4* traw      = (float4*)(ws + OFF_TRAW);
    float4* toff      = (float4*)(ws + OFF_TOFF);
    float*  tarea     = (float*) (ws + OFF_TAREA);
    float*  tscore    = (float*) (ws + OFF_TSCORE);
    float*  tclsf     = (float*) (ws + OFF_TCLSF);
    u32*    validbits = (u32*)   (ws + OFF_VALID);
    u32*    maskG     = (u32*)   (ws + OFF_MASK);
    float*  out       = (float*)d_out;

    dim3 gA((NTOT + 255) / 256, BATCH);
    decode_kernel<<<gA, 256, 0, stream>>>(ptrs, keyAll, clsAll, boxAll);
    topk_kernel<<<BATCH, 1024, 0, stream>>>(keyAll, topkey);
    gather_kernel<<<BATCH, 256, 0, stream>>>(topkey, clsAll, boxAll, traw, toff,
                                             tarea, tscore, tclsf, validbits);
    mask_kernel<<<dim3(KPAD / 8, BATCH), 256, 0, stream>>>(toff, tarea, maskG);
    scan_out_kernel<<<BATCH, 64, 0, stream>>>(maskG, validbits, traw, tscore, tclsf, out);
}